// Round 4
// baseline (542.592 us; speedup 1.0000x reference)
//
#include <hip/hip_runtime.h>

#define NB 512
#define NPG 256
#define NTOT (NB * NPG)
#define NEGMIN -3.4028234663852886e38f

// workspace layout (float offsets)
#define OFF_WNT 0       // WnT[64][16]   WnT[d][k] = Wn[k][d]
#define OFF_WCT 1024    // WcT[64][64]   WcT[d][k] = Wc[k][d]
#define OFF_W1AT 5120   // W1aT[128][64] W1aT[j][k] = W1[k][j]      (rows 0..63 of W1)
#define OFF_W1BT 13312  // W1bT[128][64] W1bT[j][k] = W1[64+k][j]   (rows 64..127)
#define OFF_BNC 21504   // bn + bc [64]
#define WS_FLOATS 21568

__global__ __launch_bounds__(256) void prep_kernel(
    const float* __restrict__ Wn, const float* __restrict__ bn,
    const float* __restrict__ Wc, const float* __restrict__ bc,
    const float* __restrict__ W1, float* __restrict__ ws)
{
    int i = blockIdx.x * 256 + threadIdx.x;
    if (i < 1024) {
        int d = i >> 4, k = i & 15;
        ws[OFF_WNT + i] = Wn[k * 64 + d];
    } else if (i < 5120) {
        int j = i - 1024; int d = j >> 6, k = j & 63;
        ws[OFF_WCT + j] = Wc[k * 64 + d];
    } else if (i < 13312) {
        int j = i - 5120; int r = j >> 6, k = j & 63;
        ws[OFF_W1AT + j] = W1[k * 128 + r];
    } else if (i < 21504) {
        int j = i - 13312; int r = j >> 6, k = j & 63;
        ws[OFF_W1BT + j] = W1[(64 + k) * 128 + r];
    } else if (i < WS_FLOATS) {
        int d = i - OFF_BNC;
        ws[OFF_BNC + d] = bn[d] + bc[d];
    }
}

// One block (512 threads) per graph; TWO threads per node split by dim-half
// (H = t>>8, wave-uniform). LDS 65.8 KB -> 2 blocks/CU possible.
//
// Occupancy law fitted to R0/R2/R3 counters: waves/SIMD = 256/VGPR on this
// chip. So the ONLY way to 16 waves/CU is VGPR=64 with ZERO spill:
//  - __launch_bounds__(512,4) -> compiler emits exactly 64 VGPRs (R2-measured)
//  - gather holds own[32]+esp[4] only; nf reloaded from global per level
//  - h-update: hnew[32] persistent accumulators, pooled row streamed from LDS
//    ONCE (16 b128), k ascending -> LDS pressure at round-0 parity
//  - MLP: h streamed from LDS per 4-j group (no h[64] reg array); an asm
//    memory clobber per group stops LICM from hoisting the row into 64 regs
//
// Numerical exactness contract: every float written is bitwise identical to
// the passing round-0 kernel (absmax 82.0 / threshold 89.6): per-output
// folds are bias-init then k-ascending FMA chains in round-0's exact order.
__global__ __launch_bounds__(512, 4) void gdqn_kernel(
    const float* __restrict__ nfg, const int* __restrict__ esrcg,
    const int* __restrict__ fmask, const float* __restrict__ ws,
    const float* __restrict__ bn, const float* __restrict__ b1,
    const float* __restrict__ W2, const float* __restrict__ b2,
    float* __restrict__ out)
{
    extern __shared__ float smem[];
    float* hsh  = smem;                     // 256*64 = 16384 (swizzled rows)
    float* part = smem + 16384;             // 256
    float* gesh = smem + 16640;             // 64
    float* rpsh = smem + 16704;             // 128
    float* redv = smem + 16832;             // 4
    int*   redi = (int*)(smem + 16836);     // 4

    const int g = blockIdx.x, t = threadIdx.x;
    const int n = t & 255;                  // node within graph
    const int H = __builtin_amdgcn_readfirstlane(t >> 8);  // wave-uniform half
    const int node = (g << 8) + n;
    const int sw = n & 15;                  // 16-slot chunk swizzle
    float* myrow = hsh + (n << 6);

    const float* WnT  = ws + OFF_WNT;
    const float* WcT  = ws + OFF_WCT;
    const float* W1aT = ws + OFF_W1AT;
    const float* bnc  = ws + OFF_BNC;

    const int dbase = H << 5;
    const int Hb = H << 7;  // byte offset of my chunk-half in a 256 B row

    // neighbor indices packed 4-per-register (values < 256) -> 4 VGPRs
    int esp[4];
    {
        const int4* p = (const int4*)(esrcg + node * 16);
        int4 a = p[0], b = p[1], c = p[2], d = p[3];
        esp[0] = (a.x&255) | ((a.y&255)<<8) | ((a.z&255)<<16) | ((a.w&255)<<24);
        esp[1] = (b.x&255) | ((b.y&255)<<8) | ((b.z&255)<<16) | ((b.w&255)<<24);
        esp[2] = (c.x&255) | ((c.y&255)<<8) | ((c.z&255)<<16) | ((c.w&255)<<24);
        esp[3] = (d.x&255) | ((d.y&255)<<8) | ((d.z&255)<<16) | ((d.w&255)<<24);
    }

    // node features -> regs; h0 = relu(bn-init fold k=0..15) for my 32 dims
    float nf[16];
    {
        const float4* p = (const float4*)(nfg + node * 16);
        float4 a = p[0], b = p[1], c = p[2], d = p[3];
        nf[0]=a.x; nf[1]=a.y; nf[2]=a.z; nf[3]=a.w;
        nf[4]=b.x; nf[5]=b.y; nf[6]=b.z; nf[7]=b.w;
        nf[8]=c.x; nf[9]=c.y; nf[10]=c.z; nf[11]=c.w;
        nf[12]=d.x; nf[13]=d.y; nf[14]=d.z; nf[15]=d.w;
    }
    #pragma unroll
    for (int c = 0; c < 8; ++c) {
        float s4[4];
        #pragma unroll
        for (int q = 0; q < 4; ++q) {
            int d = dbase + 4 * c + q;
            float s = bn[d];
            #pragma unroll
            for (int k = 0; k < 16; ++k) s = fmaf(nf[k], WnT[d * 16 + k], s);
            s4[q] = fmaxf(s, 0.0f);
        }
        ((float4*)myrow)[((H << 3) | c) ^ sw] = make_float4(s4[0], s4[1], s4[2], s4[3]);
    }
    __syncthreads();

    for (int lv = 0; lv < 3; ++lv) {
        // gather my k-half (8 chunks) of 16 neighbor rows; fold over neighbors
        // j=0..15 ascending (exact round-0 order). Live: own[32]+esp[4].
        float own[32];
        #pragma unroll
        for (int i = 0; i < 32; ++i) own[i] = 0.0f;
        const char* bp = (const char*)hsh;
        #pragma unroll
        for (int j = 0; j < 16; ++j) {
            int s = (esp[j >> 2] >> ((j & 3) * 8)) & 255;
            int vb = ((s << 8) | ((s & 15) << 4)) ^ Hb;  // swizzle folded in
            #pragma unroll
            for (int c = 0; c < 8; ++c) {
                float4 v = *(const float4*)(bp + (vb ^ (c << 4)));
                own[4*c+0] += v.x; own[4*c+1] += v.y;
                own[4*c+2] += v.z; own[4*c+3] += v.w;
            }
        }
        // reload nf (L2-resident; latency hides under the two barriers)
        {
            const float4* p = (const float4*)(nfg + node * 16);
            float4 a = p[0], b = p[1], c = p[2], d = p[3];
            nf[0]=a.x; nf[1]=a.y; nf[2]=a.z; nf[3]=a.w;
            nf[4]=b.x; nf[5]=b.y; nf[6]=b.z; nf[7]=b.w;
            nf[8]=c.x; nf[9]=c.y; nf[10]=c.z; nf[11]=c.w;
            nf[12]=d.x; nf[13]=d.y; nf[14]=d.z; nf[15]=d.w;
        }
        __syncthreads();   // all gather reads of old h done

        // exchange: write my pooled half into my row (natural dim position)
        #pragma unroll
        for (int c = 0; c < 8; ++c)
            ((float4*)myrow)[((H << 3) | c) ^ sw] =
                make_float4(own[4*c+0], own[4*c+1], own[4*c+2], own[4*c+3]);
        __syncthreads();   // both halves of pooled[n] visible

        // hnew[d] = bnc[d] -> fold nf k=0..15 -> fold pooled k=0..63 ascending
        // (pooled streamed ONCE from LDS, accumulating into all 32 outputs)
        float hnew[32];
        #pragma unroll
        for (int dq = 0; dq < 32; ++dq) {
            int d = dbase + dq;
            float s = bnc[d];
            #pragma unroll
            for (int k = 0; k < 16; ++k) s = fmaf(nf[k], WnT[d * 16 + k], s);
            hnew[dq] = s;
        }
        #pragma unroll
        for (int kc = 0; kc < 16; ++kc) {
            float4 v = ((const float4*)myrow)[kc ^ sw];
            int kb = 4 * kc;
            #pragma unroll
            for (int dq = 0; dq < 32; ++dq) {
                const float* wr = WcT + (dbase + dq) * 64;
                float s = hnew[dq];
                s = fmaf(v.x, wr[kb+0], s); s = fmaf(v.y, wr[kb+1], s);
                s = fmaf(v.z, wr[kb+2], s); s = fmaf(v.w, wr[kb+3], s);
                hnew[dq] = s;
            }
        }
        __syncthreads();   // pair finished reading pooled before h overwrite

        #pragma unroll
        for (int c = 0; c < 8; ++c)
            ((float4*)myrow)[((H << 3) | c) ^ sw] =
                make_float4(fmaxf(hnew[4*c+0], 0.0f), fmaxf(hnew[4*c+1], 0.0f),
                            fmaxf(hnew[4*c+2], 0.0f), fmaxf(hnew[4*c+3], 0.0f));
        __syncthreads();
    }

    // graph_embed = relu(column sums of h) -- exact round-0 math (t<256)
    if (t < 256) {
        int col = t & 63, v0 = (t >> 6) << 6;
        float s = 0.0f;
        for (int v = 0; v < 64; ++v) {
            int vv = v0 + v;
            s += hsh[(vv << 6) + ((((col >> 2) ^ (vv & 15)) << 2) | (col & 3))];
        }
        part[t] = s;
    }
    __syncthreads();
    if (t < 64) {
        float s = part[t] + part[t + 64] + part[t + 128] + part[t + 192];
        gesh[t] = fmaxf(s, 0.0f);
    }
    __syncthreads();
    // rep_proj[j] = b1[j] + sum_k ge[k] * W1[64+k][j]  (block-uniform MLP half)
    if (t < 128) {
        float s = b1[t];
        const float4* wr = (const float4*)(ws + OFF_W1BT + t * 64);
        #pragma unroll
        for (int c = 0; c < 16; ++c) {
            float4 w = wr[c];
            s = fmaf(gesh[4*c+0], w.x, s);
            s = fmaf(gesh[4*c+1], w.y, s);
            s = fmaf(gesh[4*c+2], w.z, s);
            s = fmaf(gesh[4*c+3], w.w, s);
        }
        rpsh[t] = s;
    }
    __syncthreads();   // rpsh ready

    if (t < 256) {
        // raw_pred: j=0..127 in groups of 4, k fold ascending via LDS stream.
        // Per-j and global j order identical to round-0's sequential fold.
        float raw = b2[0];
        for (int jq = 0; jq < 32; ++jq) {   // wave-uniform
            asm volatile("" ::: "memory");  // block LICM from hoisting the row
            int j0 = 4 * jq;
            float z0 = rpsh[j0+0], z1 = rpsh[j0+1];
            float z2 = rpsh[j0+2], z3 = rpsh[j0+3];
            const float* w0 = W1aT + (j0+0) * 64;
            const float* w1 = W1aT + (j0+1) * 64;
            const float* w2 = W1aT + (j0+2) * 64;
            const float* w3 = W1aT + (j0+3) * 64;
            #pragma unroll
            for (int kc = 0; kc < 16; ++kc) {
                float4 v = ((const float4*)myrow)[kc ^ sw];
                int kb = 4 * kc;
                z0=fmaf(v.x,w0[kb+0],z0); z0=fmaf(v.y,w0[kb+1],z0);
                z0=fmaf(v.z,w0[kb+2],z0); z0=fmaf(v.w,w0[kb+3],z0);
                z1=fmaf(v.x,w1[kb+0],z1); z1=fmaf(v.y,w1[kb+1],z1);
                z1=fmaf(v.z,w1[kb+2],z1); z1=fmaf(v.w,w1[kb+3],z1);
                z2=fmaf(v.x,w2[kb+0],z2); z2=fmaf(v.y,w2[kb+1],z2);
                z2=fmaf(v.z,w2[kb+2],z2); z2=fmaf(v.w,w2[kb+3],z2);
                z3=fmaf(v.x,w3[kb+0],z3); z3=fmaf(v.y,w3[kb+1],z3);
                z3=fmaf(v.z,w3[kb+2],z3); z3=fmaf(v.w,w3[kb+3],z3);
            }
            raw = fmaf(fmaxf(z0, 0.0f), W2[j0+0], raw);
            raw = fmaf(fmaxf(z1, 0.0f), W2[j0+1], raw);
            raw = fmaf(fmaxf(z2, 0.0f), W2[j0+2], raw);
            raw = fmaf(fmaxf(z3, 0.0f), W2[j0+3], raw);
        }
        out[512 + node] = raw;

        // masked max/argmax (first-index tie-break like jnp.argmax)
        float q = fmask[node] ? NEGMIN : raw;
        int idx = t;
        #pragma unroll
        for (int off = 32; off >= 1; off >>= 1) {
            float ov = __shfl_down(q, off, 64);
            int oi  = __shfl_down(idx, off, 64);
            if (ov > q || (ov == q && oi < idx)) { q = ov; idx = oi; }
        }
        if ((t & 63) == 0) { redv[t >> 6] = q; redi[t >> 6] = idx; }
    }
    __syncthreads();
    if (t == 0) {
        float bv = redv[0]; int bi = redi[0];
        #pragma unroll
        for (int w = 1; w < 4; ++w) {
            float v = redv[w]; int iw = redi[w];
            if (v > bv || (v == bv && iw < bi)) { bv = v; bi = iw; }
        }
        out[g] = (float)bi;             // indices (as float)
        out[512 + NTOT + g] = bv;       // values
    }
}

extern "C" void kernel_launch(void* const* d_in, const int* in_sizes, int n_in,
                              void* d_out, int out_size, void* d_ws, size_t ws_size,
                              hipStream_t stream)
{
    const float* nfg   = (const float*)d_in[0];
    const int*   esrc  = (const int*)d_in[1];
    const int*   fmask = (const int*)d_in[4];
    const float* Wn = (const float*)d_in[5];
    const float* bn = (const float*)d_in[6];
    const float* Wc = (const float*)d_in[7];
    const float* bc = (const float*)d_in[8];
    const float* W1 = (const float*)d_in[9];
    const float* b1 = (const float*)d_in[10];
    const float* W2 = (const float*)d_in[11];
    const float* b2 = (const float*)d_in[12];
    float* out = (float*)d_out;
    float* ws  = (float*)d_ws;

    prep_kernel<<<(WS_FLOATS + 255) / 256, 256, 0, stream>>>(Wn, bn, Wc, bc, W1, ws);

    size_t shmem = 16840 * sizeof(float);  // 67,360 B > 64 KB default -> opt in
    hipFuncSetAttribute((const void*)gdqn_kernel,
                        hipFuncAttributeMaxDynamicSharedMemorySize, (int)shmem);
    gdqn_kernel<<<NB, 512, shmem, stream>>>(nfg, esrc, fmask, ws, bn, b1, W2, b2, out);
}

// Round 5
// 376.145 us; speedup vs baseline: 1.4425x; 1.4425x over previous
//
#include <hip/hip_runtime.h>

#define NB 512
#define NPG 256
#define NTOT (NB * NPG)
#define NEGMIN -3.4028234663852886e38f

// workspace layout (float offsets)
#define OFF_WNT 0       // WnT[64][16]   WnT[d][k] = Wn[k][d]
#define OFF_WCT 1024    // WcT[64][64]   WcT[d][k] = Wc[k][d]
#define OFF_W1AT 5120   // W1aT[128][64] W1aT[j][k] = W1[k][j]      (rows 0..63 of W1)
#define OFF_W1BT 13312  // W1bT[128][64] W1bT[j][k] = W1[64+k][j]   (rows 64..127)
#define OFF_BNC 21504   // bn + bc [64]
#define WS_FLOATS 21568

__global__ __launch_bounds__(256) void prep_kernel(
    const float* __restrict__ Wn, const float* __restrict__ bn,
    const float* __restrict__ Wc, const float* __restrict__ bc,
    const float* __restrict__ W1, float* __restrict__ ws)
{
    int i = blockIdx.x * 256 + threadIdx.x;
    if (i < 1024) {
        int d = i >> 4, k = i & 15;
        ws[OFF_WNT + i] = Wn[k * 64 + d];
    } else if (i < 5120) {
        int j = i - 1024; int d = j >> 6, k = j & 63;
        ws[OFF_WCT + j] = Wc[k * 64 + d];
    } else if (i < 13312) {
        int j = i - 5120; int r = j >> 6, k = j & 63;
        ws[OFF_W1AT + j] = W1[k * 128 + r];
    } else if (i < 21504) {
        int j = i - 13312; int r = j >> 6, k = j & 63;
        ws[OFF_W1BT + j] = W1[(64 + k) * 128 + r];
    } else if (i < WS_FLOATS) {
        int d = i - OFF_BNC;
        ws[OFF_BNC + d] = bn[d] + bc[d];
    }
}

// R5 = the round-0 structure (256 threads/graph, VGPR 128, 2 blocks/CU —
// the best measured config; 512-thread variants either spill at VGPR 64
// (R2/R4: ~470 MB scratch traffic, HBM-bound) or lose block overlap at
// VGPR 128 (R3)) with two bitwise-preserving fixes:
//  1. 16-slot XOR chunk swizzle (sw = n&15, was n&7): measured on identical
//     gather statistics in R3/R4, conflicts 1.9e7 -> 1.2e7.
//  2. 4-way ILP on every serial fmaf chain (MLP j-loop, level matmul, h0):
//     4 independent accumulator chains interleaved; per-accumulator op
//     order unchanged -> bitwise identical, hides the 4-cyc FMA latency
//     that a single 64-deep chain exposes at only 2 waves/SIMD.
// Numerical exactness contract: every float written is bitwise identical
// to round-0 (absmax 82.0 / threshold 89.6).
__global__ __launch_bounds__(256, 2) void gdqn_kernel(
    const float* __restrict__ nfg, const int* __restrict__ esrcg,
    const int* __restrict__ fmask, const float* __restrict__ ws,
    const float* __restrict__ bn, const float* __restrict__ b1,
    const float* __restrict__ W2, const float* __restrict__ b2,
    float* __restrict__ out)
{
    extern __shared__ float smem[];
    float* hsh  = smem;                     // 256*64 = 16384 (swizzled rows)
    float* part = smem + 16384;             // 256
    float* gesh = smem + 16640;             // 64
    float* rpsh = smem + 16704;             // 128
    float* redv = smem + 16832;             // 4
    int*   redi = (int*)(smem + 16836);     // 4

    const int g = blockIdx.x, t = threadIdx.x;
    const int node = (g << 8) + t;
    const int sw = t & 15;                  // 16-slot chunk swizzle
    float* myrow = hsh + (t << 6);

    const float* WnT  = ws + OFF_WNT;
    const float* WcT  = ws + OFF_WCT;
    const float* W1aT = ws + OFF_W1AT;
    const float* bnc  = ws + OFF_BNC;

    // node features (16 floats) -> regs (static indices only)
    float nf[16];
    {
        const float4* p = (const float4*)(nfg + node * 16);
        float4 a = p[0], b = p[1], c = p[2], d = p[3];
        nf[0]=a.x; nf[1]=a.y; nf[2]=a.z; nf[3]=a.w;
        nf[4]=b.x; nf[5]=b.y; nf[6]=b.z; nf[7]=b.w;
        nf[8]=c.x; nf[9]=c.y; nf[10]=c.z; nf[11]=c.w;
        nf[12]=d.x; nf[13]=d.y; nf[14]=d.z; nf[15]=d.w;
    }
    // neighbor indices packed 4-per-register (values < 256) -> 4 VGPRs
    int esp[4];
    {
        const int4* p = (const int4*)(esrcg + node * 16);
        int4 a = p[0], b = p[1], c = p[2], d = p[3];
        esp[0] = (a.x&255) | ((a.y&255)<<8) | ((a.z&255)<<16) | ((a.w&255)<<24);
        esp[1] = (b.x&255) | ((b.y&255)<<8) | ((b.z&255)<<16) | ((b.w&255)<<24);
        esp[2] = (c.x&255) | ((c.y&255)<<8) | ((c.z&255)<<16) | ((c.w&255)<<24);
        esp[3] = (d.x&255) | ((d.y&255)<<8) | ((d.z&255)<<16) | ((d.w&255)<<24);
    }

    // h0 = relu(bn-init fold k=0..15), 4 interleaved output chains
    for (int cg = 0; cg < 16; ++cg) {       // cg wave-uniform
        int d0 = 4 * cg;
        float s0 = bn[d0+0], s1 = bn[d0+1], s2 = bn[d0+2], s3 = bn[d0+3];
        #pragma unroll
        for (int k = 0; k < 16; ++k) {
            s0 = fmaf(nf[k], WnT[(d0+0)*16 + k], s0);
            s1 = fmaf(nf[k], WnT[(d0+1)*16 + k], s1);
            s2 = fmaf(nf[k], WnT[(d0+2)*16 + k], s2);
            s3 = fmaf(nf[k], WnT[(d0+3)*16 + k], s3);
        }
        ((float4*)myrow)[cg ^ sw] = make_float4(fmaxf(s0, 0.0f), fmaxf(s1, 0.0f),
                                                fmaxf(s2, 0.0f), fmaxf(s3, 0.0f));
    }
    __syncthreads();

    for (int lv = 0; lv < 3; ++lv) {
        // gather-sum 16 neighbor rows from LDS into pooled[64] regs;
        // per-k fold over neighbors j=0..15 ascending (round-0 order)
        float pooled[64];
        #pragma unroll
        for (int i = 0; i < 64; ++i) pooled[i] = 0.0f;
        const char* bp = (const char*)hsh;
        #pragma unroll
        for (int j = 0; j < 16; ++j) {
            int s = (esp[j >> 2] >> ((j & 3) * 8)) & 255;
            int vb = (s << 8) | ((s & 15) << 4);   // swizzle folded into base
            #pragma unroll
            for (int c = 0; c < 16; ++c) {
                float4 v = *(const float4*)(bp + (vb ^ (c << 4)));
                pooled[4*c+0] += v.x; pooled[4*c+1] += v.y;
                pooled[4*c+2] += v.z; pooled[4*c+3] += v.w;
            }
        }
        __syncthreads();  // all reads of old h done before overwrite

        // h[d] = relu(bnc-init -> nf k=0..15 -> pooled k=0..63 ascending),
        // 4 interleaved output chains (per-chain order = round-0)
        for (int cg = 0; cg < 16; ++cg) {   // cg wave-uniform
            int d0 = 4 * cg;
            float s0 = bnc[d0+0], s1 = bnc[d0+1], s2 = bnc[d0+2], s3 = bnc[d0+3];
            #pragma unroll
            for (int k = 0; k < 16; ++k) {
                s0 = fmaf(nf[k], WnT[(d0+0)*16 + k], s0);
                s1 = fmaf(nf[k], WnT[(d0+1)*16 + k], s1);
                s2 = fmaf(nf[k], WnT[(d0+2)*16 + k], s2);
                s3 = fmaf(nf[k], WnT[(d0+3)*16 + k], s3);
            }
            const float* w0 = WcT + (d0+0) * 64;
            const float* w1 = WcT + (d0+1) * 64;
            const float* w2 = WcT + (d0+2) * 64;
            const float* w3 = WcT + (d0+3) * 64;
            #pragma unroll
            for (int k = 0; k < 64; ++k) {
                s0 = fmaf(pooled[k], w0[k], s0);
                s1 = fmaf(pooled[k], w1[k], s1);
                s2 = fmaf(pooled[k], w2[k], s2);
                s3 = fmaf(pooled[k], w3[k], s3);
            }
            ((float4*)myrow)[cg ^ sw] = make_float4(fmaxf(s0, 0.0f), fmaxf(s1, 0.0f),
                                                    fmaxf(s2, 0.0f), fmaxf(s3, 0.0f));
        }
        __syncthreads();
    }

    // graph_embed = relu(column sums of h)
    {
        int col = t & 63, v0 = (t >> 6) << 6;
        float s = 0.0f;
        for (int v = 0; v < 64; ++v) {
            int vv = v0 + v;
            s += hsh[(vv << 6) + ((((col >> 2) ^ (vv & 15)) << 2) | (col & 3))];
        }
        part[t] = s;
    }
    __syncthreads();
    if (t < 64) {
        float s = part[t] + part[t + 64] + part[t + 128] + part[t + 192];
        gesh[t] = fmaxf(s, 0.0f);
    }
    __syncthreads();
    // rep_proj[j] = b1[j] + sum_k ge[k] * W1[64+k][j]  (block-uniform MLP half)
    if (t < 128) {
        float s = b1[t];
        const float4* wr = (const float4*)(ws + OFF_W1BT + t * 64);
        #pragma unroll
        for (int c = 0; c < 16; ++c) {
            float4 w = wr[c];
            s = fmaf(gesh[4*c+0], w.x, s);
            s = fmaf(gesh[4*c+1], w.y, s);
            s = fmaf(gesh[4*c+2], w.z, s);
            s = fmaf(gesh[4*c+3], w.w, s);
        }
        rpsh[t] = s;
    }

    // reload this node's h from LDS into regs (pooled/nf dead here)
    float h[64];
    #pragma unroll
    for (int c = 0; c < 16; ++c) {
        float4 v = ((const float4*)myrow)[c ^ sw];
        h[4*c+0] = v.x; h[4*c+1] = v.y; h[4*c+2] = v.z; h[4*c+3] = v.w;
    }
    __syncthreads();   // rpsh ready

    // raw_pred = relu([h, rep] @ W1 + b1) @ W2 + b2, j in groups of 4 with
    // interleaved z chains; raw folds j ascending (round-0 order exactly)
    float raw = b2[0];
    for (int jq = 0; jq < 32; ++jq) {       // jq wave-uniform
        int j0 = 4 * jq;
        float z0 = rpsh[j0+0], z1 = rpsh[j0+1];
        float z2 = rpsh[j0+2], z3 = rpsh[j0+3];
        const float* w0 = W1aT + (j0+0) * 64;
        const float* w1 = W1aT + (j0+1) * 64;
        const float* w2 = W1aT + (j0+2) * 64;
        const float* w3 = W1aT + (j0+3) * 64;
        #pragma unroll
        for (int k = 0; k < 64; ++k) {
            z0 = fmaf(h[k], w0[k], z0);
            z1 = fmaf(h[k], w1[k], z1);
            z2 = fmaf(h[k], w2[k], z2);
            z3 = fmaf(h[k], w3[k], z3);
        }
        raw = fmaf(fmaxf(z0, 0.0f), W2[j0+0], raw);
        raw = fmaf(fmaxf(z1, 0.0f), W2[j0+1], raw);
        raw = fmaf(fmaxf(z2, 0.0f), W2[j0+2], raw);
        raw = fmaf(fmaxf(z3, 0.0f), W2[j0+3], raw);
    }
    out[512 + node] = raw;

    // masked max/argmax over the graph (first-index tie-break like jnp.argmax)
    float q = fmask[node] ? NEGMIN : raw;
    int idx = t;
    #pragma unroll
    for (int off = 32; off >= 1; off >>= 1) {
        float ov = __shfl_down(q, off, 64);
        int oi  = __shfl_down(idx, off, 64);
        if (ov > q || (ov == q && oi < idx)) { q = ov; idx = oi; }
    }
    if ((t & 63) == 0) { redv[t >> 6] = q; redi[t >> 6] = idx; }
    __syncthreads();
    if (t == 0) {
        float bv = redv[0]; int bi = redi[0];
        #pragma unroll
        for (int w = 1; w < 4; ++w) {
            float v = redv[w]; int iw = redi[w];
            if (v > bv || (v == bv && iw < bi)) { bv = v; bi = iw; }
        }
        out[g] = (float)bi;             // indices (as float)
        out[512 + NTOT + g] = bv;       // values
    }
}

extern "C" void kernel_launch(void* const* d_in, const int* in_sizes, int n_in,
                              void* d_out, int out_size, void* d_ws, size_t ws_size,
                              hipStream_t stream)
{
    const float* nfg   = (const float*)d_in[0];
    const int*   esrc  = (const int*)d_in[1];
    const int*   fmask = (const int*)d_in[4];
    const float* Wn = (const float*)d_in[5];
    const float* bn = (const float*)d_in[6];
    const float* Wc = (const float*)d_in[7];
    const float* bc = (const float*)d_in[8];
    const float* W1 = (const float*)d_in[9];
    const float* b1 = (const float*)d_in[10];
    const float* W2 = (const float*)d_in[11];
    const float* b2 = (const float*)d_in[12];
    float* out = (float*)d_out;
    float* ws  = (float*)d_ws;

    prep_kernel<<<(WS_FLOATS + 255) / 256, 256, 0, stream>>>(Wn, bn, Wc, bc, W1, ws);

    size_t shmem = 16840 * sizeof(float);  // 67,360 B > 64 KB default -> opt in
    hipFuncSetAttribute((const void*)gdqn_kernel,
                        hipFuncAttributeMaxDynamicSharedMemorySize, (int)shmem);
    gdqn_kernel<<<NB, 256, shmem, stream>>>(nfg, esrc, fmask, ws, bn, b1, W2, b2, out);
}